// Round 1
// baseline (885.932 us; speedup 1.0000x reference)
//
#include <hip/hip_runtime.h>
#include <hip/hip_bf16.h>
#include <cstdint>

// ---------------- CSR build ----------------

__global__ void k_hist(const int* __restrict__ dst, int E, int* __restrict__ deg) {
    int i = blockIdx.x * blockDim.x + threadIdx.x;
    if (i < E) atomicAdd(&deg[dst[i]], 1);
}

__global__ void k_scan1(const int* __restrict__ deg, int n, int* __restrict__ bsums) {
    __shared__ int s[256];
    int t = threadIdx.x;
    int i = blockIdx.x * 256 + t;
    int v = (i < n) ? deg[i] : 0;
    s[t] = v; __syncthreads();
    for (int off = 128; off > 0; off >>= 1) {
        if (t < off) s[t] += s[t + off];
        __syncthreads();
    }
    if (t == 0) bsums[blockIdx.x] = s[0];
}

// single block, inclusive->exclusive scan of up to 512 block sums
__global__ void k_scan2(const int* __restrict__ bsums, int nb, int* __restrict__ boffs) {
    __shared__ int s[512];
    int t = threadIdx.x;
    int v = (t < nb) ? bsums[t] : 0;
    s[t] = v; __syncthreads();
    for (int off = 1; off < 512; off <<= 1) {
        int nv = (t >= off) ? s[t - off] : 0;
        __syncthreads();
        s[t] += nv;
        __syncthreads();
    }
    if (t < nb) boffs[t] = s[t] - v;  // exclusive
}

__global__ void k_scan3(const int* __restrict__ deg, int n, const int* __restrict__ boffs,
                        int* __restrict__ rowst, int* __restrict__ cursor) {
    __shared__ int s[256];
    int t = threadIdx.x;
    int i = blockIdx.x * 256 + t;
    int v = (i < n) ? deg[i] : 0;
    s[t] = v; __syncthreads();
    for (int off = 1; off < 256; off <<= 1) {
        int nv = (t >= off) ? s[t - off] : 0;
        __syncthreads();
        s[t] += nv;
        __syncthreads();
    }
    int incl = s[t] + boffs[blockIdx.x];
    if (i < n) {
        int ex = incl - v;
        rowst[i] = ex;
        cursor[i] = ex;
        if (i == n - 1) rowst[n] = incl;
    }
}

__global__ void k_scatter(const int* __restrict__ src, const int* __restrict__ dst, int E,
                          int* __restrict__ cursor, int* __restrict__ col) {
    int i = blockIdx.x * blockDim.x + threadIdx.x;
    if (i < E) {
        int p = atomicAdd(&cursor[dst[i]], 1);
        col[p] = src[i];
    }
}

// ---------------- per-layer kernels ----------------

// h = x @ W  ([N,32]@[32,128]), alpha_src/dst = sum(h*att, per head of 32)
// 16 nodes per 256-thread block; 64 threads (1 wave) per node, 2 channels/thread.
__global__ void k_gemm_alpha(const float* __restrict__ x, const float* __restrict__ W,
                             const float* __restrict__ a_src, const float* __restrict__ a_dst,
                             float* __restrict__ h, float* __restrict__ alpha_src,
                             float* __restrict__ alpha_dst, int n) {
    __shared__ float Wls[32 * 128];
    __shared__ float asl[128], adl[128];
    __shared__ float xs[16][32];
    int t = threadIdx.x;
    for (int i = t; i < 32 * 128; i += 256) Wls[i] = W[i];
    if (t < 128) { asl[t] = a_src[t]; adl[t] = a_dst[t]; }
    int base = blockIdx.x * 16;
    for (int i = t; i < 16 * 32; i += 256) {
        int nn = base + i / 32;
        xs[i / 32][i % 32] = (nn < n) ? x[nn * 32 + i % 32] : 0.f;
    }
    __syncthreads();
    int lane = t & 63;
    int sub = t >> 6;           // wave id within block, 0..3
    int j2 = lane * 2;          // flattened out channel pair = head*32 + c
    for (int p = 0; p < 4; ++p) {
        int local = p * 4 + sub;
        int node = base + local;
        if (node >= n) continue;
        float acc0 = 0.f, acc1 = 0.f;
#pragma unroll
        for (int k = 0; k < 32; ++k) {
            float xv = xs[local][k];
            acc0 += xv * Wls[k * 128 + j2];
            acc1 += xv * Wls[k * 128 + j2 + 1];
        }
        *reinterpret_cast<float2*>(&h[(size_t)node * 128 + j2]) = make_float2(acc0, acc1);
        float ps = acc0 * asl[j2] + acc1 * asl[j2 + 1];
        float pd = acc0 * adl[j2] + acc1 * adl[j2 + 1];
#pragma unroll
        for (int m = 1; m < 16; m <<= 1) {
            ps += __shfl_xor(ps, m, 64);
            pd += __shfl_xor(pd, m, 64);
        }
        if ((lane & 15) == 0) {
            int head = lane >> 4;
            alpha_src[node * 4 + head] = ps;
            alpha_dst[node * 4 + head] = pd;
        }
    }
}

// one wave per dst node: single-pass softmax (no max-shift) + weighted aggregation
// + self loop + head-mean + bias + elu
__global__ void k_agg(const float* __restrict__ h, const float* __restrict__ asrc,
                      const float* __restrict__ adst, const int* __restrict__ rowst,
                      const int* __restrict__ col, const float* __restrict__ bias,
                      float* __restrict__ out, int n) {
    int wid = (int)((blockIdx.x * (size_t)blockDim.x + threadIdx.x) >> 6);
    if (wid >= n) return;
    int lane = threadIdx.x & 63;
    int head = lane >> 4;
    int c2 = (lane & 15) * 2;   // channel pair within head; lane*2 == head*32 + c2
    float ad = adst[wid * 4 + head];
    // self loop term
    float e = asrc[wid * 4 + head] + ad;
    e = e > 0.f ? e : 0.2f * e;
    float w = __expf(e);
    float2 hv = *reinterpret_cast<const float2*>(&h[(size_t)wid * 128 + lane * 2]);
    float s = w;
    float a0 = w * hv.x, a1 = w * hv.y;
    int beg = rowst[wid], end = rowst[wid + 1];
    for (int i = beg; i < end; ++i) {
        int src = col[i];
        float e2 = asrc[src * 4 + head] + ad;
        e2 = e2 > 0.f ? e2 : 0.2f * e2;
        float w2 = __expf(e2);
        float2 hs = *reinterpret_cast<const float2*>(&h[(size_t)src * 128 + lane * 2]);
        s += w2;
        a0 += w2 * hs.x;
        a1 += w2 * hs.y;
    }
    float inv = 1.f / s;
    a0 *= inv; a1 *= inv;
    // mean over 4 heads (lanes differing in bits 4,5)
    a0 += __shfl_xor(a0, 16, 64); a0 += __shfl_xor(a0, 32, 64);
    a1 += __shfl_xor(a1, 16, 64); a1 += __shfl_xor(a1, 32, 64);
    if (head == 0) {
        float o0 = a0 * 0.25f + bias[c2];
        float o1 = a1 * 0.25f + bias[c2 + 1];
        o0 = o0 > 0.f ? o0 : (__expf(o0) - 1.f);   // elu
        o1 = o1 > 0.f ? o1 : (__expf(o1) - 1.f);
        *reinterpret_cast<float2*>(&out[(size_t)wid * 32 + c2]) = make_float2(o0, o1);
    }
}

// ---------------- launch ----------------

extern "C" void kernel_launch(void* const* d_in, const int* in_sizes, int n_in,
                              void* d_out, int out_size, void* d_ws, size_t ws_size,
                              hipStream_t stream) {
    const float* x       = (const float*)d_in[0];
    const int*   ei      = (const int*)d_in[1];   // [2,E] int32
    const float* Ws      = (const float*)d_in[3]; // [3,32,128]
    const float* att_src = (const float*)d_in[4]; // [3,4,32]
    const float* att_dst = (const float*)d_in[5];
    const float* bias    = (const float*)d_in[6]; // [3,32]

    int N = in_sizes[0] / 32;
    int E = in_sizes[1] / 2;
    const int* srcv = ei;
    const int* dstv = ei + E;

    // workspace layout (~75MB)
    float* fws   = (float*)d_ws;
    float* h     = fws;                       // N*128
    float* asrc  = h + (size_t)N * 128;       // N*4
    float* adst  = asrc + (size_t)N * 4;      // N*4
    float* xbuf  = adst + (size_t)N * 4;      // N*32
    int*   deg    = (int*)(xbuf + (size_t)N * 32);  // N
    int*   rowst  = deg + N;                        // N+1
    int*   cursor = rowst + N + 1;                  // N
    int*   bsums  = cursor + N;                     // 512
    int*   boffs  = bsums + 512;                    // 512
    int*   col    = boffs + 512;                    // E

    int nb256 = (N + 255) / 256;   // 391 (<=512 for scan2)

    hipMemsetAsync(deg, 0, (size_t)N * sizeof(int), stream);
    k_hist<<<(E + 255) / 256, 256, 0, stream>>>(dstv, E, deg);
    k_scan1<<<nb256, 256, 0, stream>>>(deg, N, bsums);
    k_scan2<<<1, 512, 0, stream>>>(bsums, nb256, boffs);
    k_scan3<<<nb256, 256, 0, stream>>>(deg, N, boffs, rowst, cursor);
    k_scatter<<<(E + 255) / 256, 256, 0, stream>>>(srcv, dstv, E, cursor, col);

    for (int l = 0; l < 3; ++l) {
        const float* xin = (l == 0) ? x : xbuf;
        float* xout = (l == 2) ? (float*)d_out : xbuf;
        k_gemm_alpha<<<(N + 15) / 16, 256, 0, stream>>>(
            xin, Ws + (size_t)l * 32 * 128, att_src + l * 128, att_dst + l * 128,
            h, asrc, adst, N);
        k_agg<<<(N + 3) / 4, 256, 0, stream>>>(
            h, asrc, adst, rowst, col, bias + l * 32, xout, N);
    }
}

// Round 2
// 737.135 us; speedup vs baseline: 1.2019x; 1.2019x over previous
//
#include <hip/hip_runtime.h>
#include <hip/hip_bf16.h>
#include <cstdint>

// ---------------- CSR build ----------------

__global__ void k_hist(const int* __restrict__ dst, int E, int* __restrict__ deg) {
    int i = blockIdx.x * blockDim.x + threadIdx.x;
    if (i < E) atomicAdd(&deg[dst[i]], 1);
}

__global__ void k_scan1(const int* __restrict__ deg, int n, int* __restrict__ bsums) {
    __shared__ int s[256];
    int t = threadIdx.x;
    int i = blockIdx.x * 256 + t;
    int v = (i < n) ? deg[i] : 0;
    s[t] = v; __syncthreads();
    for (int off = 128; off > 0; off >>= 1) {
        if (t < off) s[t] += s[t + off];
        __syncthreads();
    }
    if (t == 0) bsums[blockIdx.x] = s[0];
}

// single block, inclusive->exclusive scan of up to 512 block sums
__global__ void k_scan2(const int* __restrict__ bsums, int nb, int* __restrict__ boffs) {
    __shared__ int s[512];
    int t = threadIdx.x;
    int v = (t < nb) ? bsums[t] : 0;
    s[t] = v; __syncthreads();
    for (int off = 1; off < 512; off <<= 1) {
        int nv = (t >= off) ? s[t - off] : 0;
        __syncthreads();
        s[t] += nv;
        __syncthreads();
    }
    if (t < nb) boffs[t] = s[t] - v;  // exclusive
}

__global__ void k_scan3(const int* __restrict__ deg, int n, const int* __restrict__ boffs,
                        int* __restrict__ rowst, int* __restrict__ cursor) {
    __shared__ int s[256];
    int t = threadIdx.x;
    int i = blockIdx.x * 256 + t;
    int v = (i < n) ? deg[i] : 0;
    s[t] = v; __syncthreads();
    for (int off = 1; off < 256; off <<= 1) {
        int nv = (t >= off) ? s[t - off] : 0;
        __syncthreads();
        s[t] += nv;
        __syncthreads();
    }
    int incl = s[t] + boffs[blockIdx.x];
    if (i < n) {
        int ex = incl - v;
        rowst[i] = ex;
        cursor[i] = ex;
        if (i == n - 1) rowst[n] = incl;
    }
}

__global__ void k_scatter(const int* __restrict__ src, const int* __restrict__ dst, int E,
                          int* __restrict__ cursor, int* __restrict__ col) {
    int i = blockIdx.x * blockDim.x + threadIdx.x;
    if (i < E) {
        int p = atomicAdd(&cursor[dst[i]], 1);
        col[p] = src[i];
    }
}

// ---------------- per-layer kernels ----------------

// h = x @ W  ([N,32]@[32,128]), alpha_src/dst = sum(h*att, per head of 32)
// 16 nodes per 256-thread block; 64 threads (1 wave) per node, 2 channels/thread.
__global__ void k_gemm_alpha(const float* __restrict__ x, const float* __restrict__ W,
                             const float* __restrict__ a_src, const float* __restrict__ a_dst,
                             float* __restrict__ h, float* __restrict__ alpha_src,
                             float* __restrict__ alpha_dst, int n) {
    __shared__ float Wls[32 * 128];
    __shared__ float asl[128], adl[128];
    __shared__ float xs[16][32];
    int t = threadIdx.x;
    for (int i = t; i < 32 * 128; i += 256) Wls[i] = W[i];
    if (t < 128) { asl[t] = a_src[t]; adl[t] = a_dst[t]; }
    int base = blockIdx.x * 16;
    for (int i = t; i < 16 * 32; i += 256) {
        int nn = base + i / 32;
        xs[i / 32][i % 32] = (nn < n) ? x[nn * 32 + i % 32] : 0.f;
    }
    __syncthreads();
    int lane = t & 63;
    int sub = t >> 6;           // wave id within block, 0..3
    int j2 = lane * 2;          // flattened out channel pair = head*32 + c
    for (int p = 0; p < 4; ++p) {
        int local = p * 4 + sub;
        int node = base + local;
        if (node >= n) continue;
        float acc0 = 0.f, acc1 = 0.f;
#pragma unroll
        for (int k = 0; k < 32; ++k) {
            float xv = xs[local][k];
            acc0 += xv * Wls[k * 128 + j2];
            acc1 += xv * Wls[k * 128 + j2 + 1];
        }
        *reinterpret_cast<float2*>(&h[(size_t)node * 128 + j2]) = make_float2(acc0, acc1);
        float ps = acc0 * asl[j2] + acc1 * asl[j2 + 1];
        float pd = acc0 * adl[j2] + acc1 * adl[j2 + 1];
#pragma unroll
        for (int m = 1; m < 16; m <<= 1) {
            ps += __shfl_xor(ps, m, 64);
            pd += __shfl_xor(pd, m, 64);
        }
        if ((lane & 15) == 0) {
            int head = lane >> 4;
            alpha_src[node * 4 + head] = ps;
            alpha_dst[node * 4 + head] = pd;
        }
    }
}

__device__ __forceinline__ float lrelu_exp(float e) {
    e = e > 0.f ? e : 0.2f * e;
    return __expf(e);
}

// one wave per dst node: single-pass softmax (no max-shift) + weighted aggregation
// + self loop + head-mean + bias + elu.  Edge loop unrolled x4 for MLP.
__global__ void k_agg(const float* __restrict__ h, const float* __restrict__ asrc,
                      const float* __restrict__ adst, const int* __restrict__ rowst,
                      const int* __restrict__ col, const float* __restrict__ bias,
                      float* __restrict__ out, int n) {
    int wid = (int)((blockIdx.x * (size_t)blockDim.x + threadIdx.x) >> 6);
    if (wid >= n) return;
    int lane = threadIdx.x & 63;
    int head = lane >> 4;
    int c2 = (lane & 15) * 2;   // channel pair within head; lane*2 == head*32 + c2
    float ad = adst[wid * 4 + head];
    // self loop term
    float w = lrelu_exp(asrc[wid * 4 + head] + ad);
    float2 hv = *reinterpret_cast<const float2*>(&h[(size_t)wid * 128 + lane * 2]);
    float s = w;
    float a0 = w * hv.x, a1 = w * hv.y;
    int beg = rowst[wid], end = rowst[wid + 1];
    int i = beg;
    for (; i + 4 <= end; i += 4) {
        int s0 = col[i], s1 = col[i + 1], s2 = col[i + 2], s3 = col[i + 3];
        float x0 = asrc[s0 * 4 + head];
        float x1 = asrc[s1 * 4 + head];
        float x2 = asrc[s2 * 4 + head];
        float x3 = asrc[s3 * 4 + head];
        float2 h0 = *reinterpret_cast<const float2*>(&h[(size_t)s0 * 128 + lane * 2]);
        float2 h1 = *reinterpret_cast<const float2*>(&h[(size_t)s1 * 128 + lane * 2]);
        float2 h2 = *reinterpret_cast<const float2*>(&h[(size_t)s2 * 128 + lane * 2]);
        float2 h3 = *reinterpret_cast<const float2*>(&h[(size_t)s3 * 128 + lane * 2]);
        float w0 = lrelu_exp(x0 + ad);
        float w1 = lrelu_exp(x1 + ad);
        float w2 = lrelu_exp(x2 + ad);
        float w3 = lrelu_exp(x3 + ad);
        s += w0 + w1 + w2 + w3;
        a0 += w0 * h0.x; a1 += w0 * h0.y;
        a0 += w1 * h1.x; a1 += w1 * h1.y;
        a0 += w2 * h2.x; a1 += w2 * h2.y;
        a0 += w3 * h3.x; a1 += w3 * h3.y;
    }
    for (; i < end; ++i) {
        int src = col[i];
        float w2 = lrelu_exp(asrc[src * 4 + head] + ad);
        float2 hs = *reinterpret_cast<const float2*>(&h[(size_t)src * 128 + lane * 2]);
        s += w2;
        a0 += w2 * hs.x;
        a1 += w2 * hs.y;
    }
    float inv = 1.f / s;
    a0 *= inv; a1 *= inv;
    // mean over 4 heads (lanes differing in bits 4,5)
    a0 += __shfl_xor(a0, 16, 64); a0 += __shfl_xor(a0, 32, 64);
    a1 += __shfl_xor(a1, 16, 64); a1 += __shfl_xor(a1, 32, 64);
    if (head == 0) {
        float o0 = a0 * 0.25f + bias[c2];
        float o1 = a1 * 0.25f + bias[c2 + 1];
        o0 = o0 > 0.f ? o0 : (__expf(o0) - 1.f);   // elu
        o1 = o1 > 0.f ? o1 : (__expf(o1) - 1.f);
        *reinterpret_cast<float2*>(&out[(size_t)wid * 32 + c2]) = make_float2(o0, o1);
    }
}

// ---------------- launch ----------------

extern "C" void kernel_launch(void* const* d_in, const int* in_sizes, int n_in,
                              void* d_out, int out_size, void* d_ws, size_t ws_size,
                              hipStream_t stream) {
    const float* x       = (const float*)d_in[0];
    const int*   ei      = (const int*)d_in[1];   // [2,E] int32
    const float* Ws      = (const float*)d_in[3]; // [3,32,128]
    const float* att_src = (const float*)d_in[4]; // [3,4,32]
    const float* att_dst = (const float*)d_in[5];
    const float* bias    = (const float*)d_in[6]; // [3,32]

    int N = in_sizes[0] / 32;
    int E = in_sizes[1] / 2;
    const int* srcv = ei;
    const int* dstv = ei + E;

    // workspace layout (~75MB)
    float* fws   = (float*)d_ws;
    float* h     = fws;                       // N*128
    float* asrc  = h + (size_t)N * 128;       // N*4
    float* adst  = asrc + (size_t)N * 4;      // N*4
    float* xbuf  = adst + (size_t)N * 4;      // N*32
    int*   deg    = (int*)(xbuf + (size_t)N * 32);  // N
    int*   rowst  = deg + N;                        // N+1
    int*   cursor = rowst + N + 1;                  // N
    int*   bsums  = cursor + N;                     // 512
    int*   boffs  = bsums + 512;                    // 512
    int*   col    = boffs + 512;                    // E

    int nb256 = (N + 255) / 256;   // 391 (<=512 for scan2)

    hipMemsetAsync(deg, 0, (size_t)N * sizeof(int), stream);
    k_hist<<<(E + 255) / 256, 256, 0, stream>>>(dstv, E, deg);
    k_scan1<<<nb256, 256, 0, stream>>>(deg, N, bsums);
    k_scan2<<<1, 512, 0, stream>>>(bsums, nb256, boffs);
    k_scan3<<<nb256, 256, 0, stream>>>(deg, N, boffs, rowst, cursor);
    k_scatter<<<(E + 255) / 256, 256, 0, stream>>>(srcv, dstv, E, cursor, col);

    for (int l = 0; l < 3; ++l) {
        const float* xin = (l == 0) ? x : xbuf;
        float* xout = (l == 2) ? (float*)d_out : xbuf;
        k_gemm_alpha<<<(N + 15) / 16, 256, 0, stream>>>(
            xin, Ws + (size_t)l * 32 * 128, att_src + l * 128, att_dst + l * 128,
            h, asrc, adst, N);
        k_agg<<<(N + 3) / 4, 256, 0, stream>>>(
            h, asrc, adst, rowst, col, bias + l * 32, xout, N);
    }
}

// Round 3
// 734.660 us; speedup vs baseline: 1.2059x; 1.0034x over previous
//
#include <hip/hip_runtime.h>
#include <hip/hip_bf16.h>
#include <cstdint>

// ---------------- CSR build ----------------

__global__ void k_hist(const int* __restrict__ dst, int E, int* __restrict__ deg) {
    int i = blockIdx.x * blockDim.x + threadIdx.x;
    if (i < E) atomicAdd(&deg[dst[i]], 1);
}

__global__ void k_scan1(const int* __restrict__ deg, int n, int* __restrict__ bsums) {
    __shared__ int s[256];
    int t = threadIdx.x;
    int i = blockIdx.x * 256 + t;
    int v = (i < n) ? deg[i] : 0;
    s[t] = v; __syncthreads();
    for (int off = 128; off > 0; off >>= 1) {
        if (t < off) s[t] += s[t + off];
        __syncthreads();
    }
    if (t == 0) bsums[blockIdx.x] = s[0];
}

// single block, inclusive->exclusive scan of up to 512 block sums
__global__ void k_scan2(const int* __restrict__ bsums, int nb, int* __restrict__ boffs) {
    __shared__ int s[512];
    int t = threadIdx.x;
    int v = (t < nb) ? bsums[t] : 0;
    s[t] = v; __syncthreads();
    for (int off = 1; off < 512; off <<= 1) {
        int nv = (t >= off) ? s[t - off] : 0;
        __syncthreads();
        s[t] += nv;
        __syncthreads();
    }
    if (t < nb) boffs[t] = s[t] - v;  // exclusive
}

__global__ void k_scan3(const int* __restrict__ deg, int n, const int* __restrict__ boffs,
                        int* __restrict__ rowst, int* __restrict__ cursor) {
    __shared__ int s[256];
    int t = threadIdx.x;
    int i = blockIdx.x * 256 + t;
    int v = (i < n) ? deg[i] : 0;
    s[t] = v; __syncthreads();
    for (int off = 1; off < 256; off <<= 1) {
        int nv = (t >= off) ? s[t - off] : 0;
        __syncthreads();
        s[t] += nv;
        __syncthreads();
    }
    int incl = s[t] + boffs[blockIdx.x];
    if (i < n) {
        int ex = incl - v;
        rowst[i] = ex;
        cursor[i] = ex;
        if (i == n - 1) rowst[n] = incl;
    }
}

__global__ void k_scatter(const int* __restrict__ src, const int* __restrict__ dst, int E,
                          int* __restrict__ cursor, int* __restrict__ col) {
    int i = blockIdx.x * blockDim.x + threadIdx.x;
    if (i < E) {
        int p = atomicAdd(&cursor[dst[i]], 1);
        col[p] = src[i];
    }
}

// ---------------- per-layer kernels ----------------

// h = x @ W  ([N,32]@[32,128]), alpha_src/dst = sum(h*att, per head of 32)
// 16 nodes per 256-thread block; 64 threads (1 wave) per node, 2 channels/thread.
__global__ void k_gemm_alpha(const float* __restrict__ x, const float* __restrict__ W,
                             const float* __restrict__ a_src, const float* __restrict__ a_dst,
                             float* __restrict__ h, float* __restrict__ alpha_src,
                             float* __restrict__ alpha_dst, int n) {
    __shared__ float Wls[32 * 128];
    __shared__ float asl[128], adl[128];
    __shared__ float xs[16][32];
    int t = threadIdx.x;
    for (int i = t; i < 32 * 128; i += 256) Wls[i] = W[i];
    if (t < 128) { asl[t] = a_src[t]; adl[t] = a_dst[t]; }
    int base = blockIdx.x * 16;
    for (int i = t; i < 16 * 32; i += 256) {
        int nn = base + i / 32;
        xs[i / 32][i % 32] = (nn < n) ? x[nn * 32 + i % 32] : 0.f;
    }
    __syncthreads();
    int lane = t & 63;
    int sub = t >> 6;           // wave id within block, 0..3
    int j2 = lane * 2;          // flattened out channel pair = head*32 + c
    for (int p = 0; p < 4; ++p) {
        int local = p * 4 + sub;
        int node = base + local;
        if (node >= n) continue;
        float acc0 = 0.f, acc1 = 0.f;
#pragma unroll
        for (int k = 0; k < 32; ++k) {
            float xv = xs[local][k];
            acc0 += xv * Wls[k * 128 + j2];
            acc1 += xv * Wls[k * 128 + j2 + 1];
        }
        *reinterpret_cast<float2*>(&h[(size_t)node * 128 + j2]) = make_float2(acc0, acc1);
        float ps = acc0 * asl[j2] + acc1 * asl[j2 + 1];
        float pd = acc0 * adl[j2] + acc1 * adl[j2 + 1];
#pragma unroll
        for (int m = 1; m < 16; m <<= 1) {
            ps += __shfl_xor(ps, m, 64);
            pd += __shfl_xor(pd, m, 64);
        }
        if ((lane & 15) == 0) {
            int head = lane >> 4;
            alpha_src[node * 4 + head] = ps;
            alpha_dst[node * 4 + head] = pd;
        }
    }
}

__device__ __forceinline__ float lrelu_exp(float e) {
    e = e > 0.f ? e : 0.2f * e;
    return __expf(e);
}

// one wave per dst node; two edges in flight per gather step (one per half-wave),
// float4 (16B) h-row loads; unroll x4 => 8 edge rows in flight per wave.
// single-pass softmax (no max-shift) + self loop + head-mean + bias + elu.
__global__ void k_agg(const float* __restrict__ h, const float* __restrict__ asrc,
                      const float* __restrict__ adst, const int* __restrict__ rowst,
                      const int* __restrict__ col, const float* __restrict__ bias,
                      float* __restrict__ out, int n) {
    int wid = (int)((blockIdx.x * (size_t)blockDim.x + threadIdx.x) >> 6);
    if (wid >= n) return;
    int lane = threadIdx.x & 63;
    int half = lane >> 5;       // which edge of the pair this half-wave handles
    int q = lane & 31;          // channel quad: flattened channels 4q..4q+3
    int head = q >> 3;
    float ad = adst[wid * 4 + head];

    float4 acc = make_float4(0.f, 0.f, 0.f, 0.f);
    float s = 0.f;
    if (half == 0) {  // self loop counted once
        float w = lrelu_exp(asrc[wid * 4 + head] + ad);
        float4 hv = *reinterpret_cast<const float4*>(&h[(size_t)wid * 128 + q * 4]);
        s = w;
        acc.x = w * hv.x; acc.y = w * hv.y; acc.z = w * hv.z; acc.w = w * hv.w;
    }

    int beg = rowst[wid], end = rowst[wid + 1];
    int i = beg;
    for (; i + 8 <= end; i += 8) {
        int base = i + half * 4;
        int s0 = col[base], s1 = col[base + 1], s2 = col[base + 2], s3 = col[base + 3];
        float x0 = asrc[s0 * 4 + head];
        float x1 = asrc[s1 * 4 + head];
        float x2 = asrc[s2 * 4 + head];
        float x3 = asrc[s3 * 4 + head];
        float4 h0 = *reinterpret_cast<const float4*>(&h[(size_t)s0 * 128 + q * 4]);
        float4 h1 = *reinterpret_cast<const float4*>(&h[(size_t)s1 * 128 + q * 4]);
        float4 h2 = *reinterpret_cast<const float4*>(&h[(size_t)s2 * 128 + q * 4]);
        float4 h3 = *reinterpret_cast<const float4*>(&h[(size_t)s3 * 128 + q * 4]);
        float w0 = lrelu_exp(x0 + ad);
        float w1 = lrelu_exp(x1 + ad);
        float w2 = lrelu_exp(x2 + ad);
        float w3 = lrelu_exp(x3 + ad);
        s += w0 + w1 + w2 + w3;
        acc.x += w0 * h0.x + w1 * h1.x + w2 * h2.x + w3 * h3.x;
        acc.y += w0 * h0.y + w1 * h1.y + w2 * h2.y + w3 * h3.y;
        acc.z += w0 * h0.z + w1 * h1.z + w2 * h2.z + w3 * h3.z;
        acc.w += w0 * h0.w + w1 * h1.w + w2 * h2.w + w3 * h3.w;
    }
    for (; i + 2 <= end; i += 2) {
        int sidx = col[i + half];
        float w = lrelu_exp(asrc[sidx * 4 + head] + ad);
        float4 hv = *reinterpret_cast<const float4*>(&h[(size_t)sidx * 128 + q * 4]);
        s += w;
        acc.x += w * hv.x; acc.y += w * hv.y; acc.z += w * hv.z; acc.w += w * hv.w;
    }
    if (i < end && half == 0) {   // odd remainder: half 0 only
        int sidx = col[i];
        float w = lrelu_exp(asrc[sidx * 4 + head] + ad);
        float4 hv = *reinterpret_cast<const float4*>(&h[(size_t)sidx * 128 + q * 4]);
        s += w;
        acc.x += w * hv.x; acc.y += w * hv.y; acc.z += w * hv.z; acc.w += w * hv.w;
    }

    // combine the two half-wave partials
    s += __shfl_xor(s, 32, 64);
    acc.x += __shfl_xor(acc.x, 32, 64);
    acc.y += __shfl_xor(acc.y, 32, 64);
    acc.z += __shfl_xor(acc.z, 32, 64);
    acc.w += __shfl_xor(acc.w, 32, 64);
    float inv = 1.f / s;
    acc.x *= inv; acc.y *= inv; acc.z *= inv; acc.w *= inv;
    // head mean: lanes q, q^8, q^16, q^24 hold heads 0..3 of channel group q&7
    acc.x += __shfl_xor(acc.x, 8, 64);  acc.x += __shfl_xor(acc.x, 16, 64);
    acc.y += __shfl_xor(acc.y, 8, 64);  acc.y += __shfl_xor(acc.y, 16, 64);
    acc.z += __shfl_xor(acc.z, 8, 64);  acc.z += __shfl_xor(acc.z, 16, 64);
    acc.w += __shfl_xor(acc.w, 8, 64);  acc.w += __shfl_xor(acc.w, 16, 64);
    if (lane < 8) {
        float4 b4 = *reinterpret_cast<const float4*>(&bias[lane * 4]);
        float o0 = acc.x * 0.25f + b4.x;
        float o1 = acc.y * 0.25f + b4.y;
        float o2 = acc.z * 0.25f + b4.z;
        float o3 = acc.w * 0.25f + b4.w;
        o0 = o0 > 0.f ? o0 : (__expf(o0) - 1.f);
        o1 = o1 > 0.f ? o1 : (__expf(o1) - 1.f);
        o2 = o2 > 0.f ? o2 : (__expf(o2) - 1.f);
        o3 = o3 > 0.f ? o3 : (__expf(o3) - 1.f);
        *reinterpret_cast<float4*>(&out[(size_t)wid * 32 + lane * 4]) =
            make_float4(o0, o1, o2, o3);
    }
}

// ---------------- launch ----------------

extern "C" void kernel_launch(void* const* d_in, const int* in_sizes, int n_in,
                              void* d_out, int out_size, void* d_ws, size_t ws_size,
                              hipStream_t stream) {
    const float* x       = (const float*)d_in[0];
    const int*   ei      = (const int*)d_in[1];   // [2,E] int32
    const float* Ws      = (const float*)d_in[3]; // [3,32,128]
    const float* att_src = (const float*)d_in[4]; // [3,4,32]
    const float* att_dst = (const float*)d_in[5];
    const float* bias    = (const float*)d_in[6]; // [3,32]

    int N = in_sizes[0] / 32;
    int E = in_sizes[1] / 2;
    const int* srcv = ei;
    const int* dstv = ei + E;

    // workspace layout (~75MB)
    float* fws   = (float*)d_ws;
    float* h     = fws;                       // N*128
    float* asrc  = h + (size_t)N * 128;       // N*4
    float* adst  = asrc + (size_t)N * 4;      // N*4
    float* xbuf  = adst + (size_t)N * 4;      // N*32
    int*   deg    = (int*)(xbuf + (size_t)N * 32);  // N
    int*   rowst  = deg + N;                        // N+1
    int*   cursor = rowst + N + 1;                  // N
    int*   bsums  = cursor + N;                     // 512
    int*   boffs  = bsums + 512;                    // 512
    int*   col    = boffs + 512;                    // E

    int nb256 = (N + 255) / 256;   // 391 (<=512 for scan2)

    hipMemsetAsync(deg, 0, (size_t)N * sizeof(int), stream);
    k_hist<<<(E + 255) / 256, 256, 0, stream>>>(dstv, E, deg);
    k_scan1<<<nb256, 256, 0, stream>>>(deg, N, bsums);
    k_scan2<<<1, 512, 0, stream>>>(bsums, nb256, boffs);
    k_scan3<<<nb256, 256, 0, stream>>>(deg, N, boffs, rowst, cursor);
    k_scatter<<<(E + 255) / 256, 256, 0, stream>>>(srcv, dstv, E, cursor, col);

    for (int l = 0; l < 3; ++l) {
        const float* xin = (l == 0) ? x : xbuf;
        float* xout = (l == 2) ? (float*)d_out : xbuf;
        k_gemm_alpha<<<(N + 15) / 16, 256, 0, stream>>>(
            xin, Ws + (size_t)l * 32 * 128, att_src + l * 128, att_dst + l * 128,
            h, asrc, adst, N);
        k_agg<<<(N + 3) / 4, 256, 0, stream>>>(
            h, asrc, adst, rowst, col, bias + l * 32, xout, N);
    }
}

// Round 4
// 576.153 us; speedup vs baseline: 1.5377x; 1.2751x over previous
//
#include <hip/hip_runtime.h>
#include <hip/hip_bf16.h>
#include <hip/hip_fp16.h>
#include <cstdint>

// ---------------- CSR build ----------------

__global__ void k_scan1(const int* __restrict__ deg, int n, int* __restrict__ bsums) {
    __shared__ int s[256];
    int t = threadIdx.x;
    int i = blockIdx.x * 256 + t;
    int v = (i < n) ? deg[i] : 0;
    s[t] = v; __syncthreads();
    for (int off = 128; off > 0; off >>= 1) {
        if (t < off) s[t] += s[t + off];
        __syncthreads();
    }
    if (t == 0) bsums[blockIdx.x] = s[0];
}

// single block, inclusive->exclusive scan of up to 512 block sums
__global__ void k_scan2(const int* __restrict__ bsums, int nb, int* __restrict__ boffs) {
    __shared__ int s[512];
    int t = threadIdx.x;
    int v = (t < nb) ? bsums[t] : 0;
    s[t] = v; __syncthreads();
    for (int off = 1; off < 512; off <<= 1) {
        int nv = (t >= off) ? s[t - off] : 0;
        __syncthreads();
        s[t] += nv;
        __syncthreads();
    }
    if (t < nb) boffs[t] = s[t] - v;  // exclusive
}

__global__ void k_scan3(const int* __restrict__ deg, int n, const int* __restrict__ boffs,
                        int* __restrict__ rowst, int* __restrict__ cursor) {
    __shared__ int s[256];
    int t = threadIdx.x;
    int i = blockIdx.x * 256 + t;
    int v = (i < n) ? deg[i] : 0;
    s[t] = v; __syncthreads();
    for (int off = 1; off < 256; off <<= 1) {
        int nv = (t >= off) ? s[t - off] : 0;
        __syncthreads();
        s[t] += nv;
        __syncthreads();
    }
    int incl = s[t] + boffs[blockIdx.x];
    if (i < n) {
        int ex = incl - v;
        rowst[i] = ex;
        cursor[i] = ex;
        if (i == n - 1) rowst[n] = incl;
    }
}

__global__ void k_scatter(const int* __restrict__ src, const int* __restrict__ dst, int E,
                          int* __restrict__ cursor, int* __restrict__ col) {
    int i4 = (blockIdx.x * blockDim.x + threadIdx.x) * 4;
    if (i4 + 4 <= E) {
        int4 s4 = *reinterpret_cast<const int4*>(src + i4);
        int4 d4 = *reinterpret_cast<const int4*>(dst + i4);
        int p0 = atomicAdd(&cursor[d4.x], 1);
        int p1 = atomicAdd(&cursor[d4.y], 1);
        int p2 = atomicAdd(&cursor[d4.z], 1);
        int p3 = atomicAdd(&cursor[d4.w], 1);
        col[p0] = s4.x; col[p1] = s4.y; col[p2] = s4.z; col[p3] = s4.w;
    } else {
        for (int i = i4; i < E; ++i) {
            int p = atomicAdd(&cursor[dst[i]], 1);
            col[p] = src[i];
        }
    }
}

// ---------------- per-layer kernels ----------------

// Fused: blocks [0,gemmBlocks) do GEMM+alpha; blocks beyond do the edge histogram
// (layer 0 only). h stored as fp16 (h16), alphas stay fp32.
// GEMM: h = x @ W ([N,32]@[32,128]); 16 nodes per 256-thread block, 1 wave/node.
__global__ void k_gemm_alpha(const float* __restrict__ x, const float* __restrict__ W,
                             const float* __restrict__ a_src, const float* __restrict__ a_dst,
                             __half* __restrict__ h16, float* __restrict__ alpha_src,
                             float* __restrict__ alpha_dst, int n,
                             const int* __restrict__ dstv, int E, int* __restrict__ deg,
                             int gemmBlocks) {
    if ((int)blockIdx.x >= gemmBlocks) {
        int b = blockIdx.x - gemmBlocks;
        int i4 = (b * 256 + threadIdx.x) * 4;
        if (i4 + 4 <= E) {
            int4 d4 = *reinterpret_cast<const int4*>(dstv + i4);
            atomicAdd(&deg[d4.x], 1);
            atomicAdd(&deg[d4.y], 1);
            atomicAdd(&deg[d4.z], 1);
            atomicAdd(&deg[d4.w], 1);
        } else {
            for (int i = i4; i < E; ++i) atomicAdd(&deg[dstv[i]], 1);
        }
        return;
    }
    __shared__ float Wls[32 * 128];
    __shared__ float asl[128], adl[128];
    __shared__ float xs[16][32];
    int t = threadIdx.x;
    for (int i = t; i < 32 * 128; i += 256) Wls[i] = W[i];
    if (t < 128) { asl[t] = a_src[t]; adl[t] = a_dst[t]; }
    int base = blockIdx.x * 16;
    for (int i = t; i < 16 * 32; i += 256) {
        int nn = base + i / 32;
        xs[i / 32][i % 32] = (nn < n) ? x[nn * 32 + i % 32] : 0.f;
    }
    __syncthreads();
    int lane = t & 63;
    int sub = t >> 6;           // wave id within block, 0..3
    int j2 = lane * 2;          // flattened out channel pair = head*32 + c
    for (int p = 0; p < 4; ++p) {
        int local = p * 4 + sub;
        int node = base + local;
        if (node >= n) continue;
        float acc0 = 0.f, acc1 = 0.f;
#pragma unroll
        for (int k = 0; k < 32; ++k) {
            float xv = xs[local][k];
            acc0 += xv * Wls[k * 128 + j2];
            acc1 += xv * Wls[k * 128 + j2 + 1];
        }
        *reinterpret_cast<__half2*>(h16 + (size_t)node * 128 + j2) =
            __floats2half2_rn(acc0, acc1);
        float ps = acc0 * asl[j2] + acc1 * asl[j2 + 1];
        float pd = acc0 * adl[j2] + acc1 * adl[j2 + 1];
#pragma unroll
        for (int m = 1; m < 16; m <<= 1) {
            ps += __shfl_xor(ps, m, 64);
            pd += __shfl_xor(pd, m, 64);
        }
        if ((lane & 15) == 0) {
            int head = lane >> 4;
            alpha_src[node * 4 + head] = ps;
            alpha_dst[node * 4 + head] = pd;
        }
    }
}

__device__ __forceinline__ float lrelu_exp(float e) {
    e = e > 0.f ? e : 0.2f * e;
    return __expf(e);
}

__device__ __forceinline__ float4 h16_to_f4(uint2 v) {
    float2 fa = __half22float2(*reinterpret_cast<__half2*>(&v.x));
    float2 fb = __half22float2(*reinterpret_cast<__half2*>(&v.y));
    return make_float4(fa.x, fa.y, fb.x, fb.y);
}

// one wave per dst node; two edges in flight per gather step (one per half-wave),
// fp16 h rows (256B), uint2 (8B) loads; unroll x4 => 8 edge rows in flight per wave.
// single-pass softmax (no max-shift) + self loop + head-mean + bias + elu.
__global__ void k_agg(const __half* __restrict__ h16, const float* __restrict__ asrc,
                      const float* __restrict__ adst, const int* __restrict__ rowst,
                      const int* __restrict__ col, const float* __restrict__ bias,
                      float* __restrict__ out, int n) {
    int wid = (int)((blockIdx.x * (size_t)blockDim.x + threadIdx.x) >> 6);
    if (wid >= n) return;
    int lane = threadIdx.x & 63;
    int half = lane >> 5;       // which edge of the pair this half-wave handles
    int q = lane & 31;          // channel quad: flattened channels 4q..4q+3
    int head = q >> 3;
    float ad = adst[wid * 4 + head];

    float4 acc = make_float4(0.f, 0.f, 0.f, 0.f);
    float s = 0.f;
    if (half == 0) {  // self loop counted once
        float w = lrelu_exp(asrc[wid * 4 + head] + ad);
        uint2 v = *reinterpret_cast<const uint2*>(h16 + (size_t)wid * 128 + q * 4);
        float4 hv = h16_to_f4(v);
        s = w;
        acc.x = w * hv.x; acc.y = w * hv.y; acc.z = w * hv.z; acc.w = w * hv.w;
    }

    int beg = rowst[wid], end = rowst[wid + 1];
    int i = beg;
    for (; i + 8 <= end; i += 8) {
        int base = i + half * 4;
        int s0 = col[base], s1 = col[base + 1], s2 = col[base + 2], s3 = col[base + 3];
        float x0 = asrc[s0 * 4 + head];
        float x1 = asrc[s1 * 4 + head];
        float x2 = asrc[s2 * 4 + head];
        float x3 = asrc[s3 * 4 + head];
        uint2 v0 = *reinterpret_cast<const uint2*>(h16 + (size_t)s0 * 128 + q * 4);
        uint2 v1 = *reinterpret_cast<const uint2*>(h16 + (size_t)s1 * 128 + q * 4);
        uint2 v2 = *reinterpret_cast<const uint2*>(h16 + (size_t)s2 * 128 + q * 4);
        uint2 v3 = *reinterpret_cast<const uint2*>(h16 + (size_t)s3 * 128 + q * 4);
        float w0 = lrelu_exp(x0 + ad);
        float w1 = lrelu_exp(x1 + ad);
        float w2 = lrelu_exp(x2 + ad);
        float w3 = lrelu_exp(x3 + ad);
        float4 h0 = h16_to_f4(v0), h1 = h16_to_f4(v1), h2 = h16_to_f4(v2), h3 = h16_to_f4(v3);
        s += w0 + w1 + w2 + w3;
        acc.x += w0 * h0.x + w1 * h1.x + w2 * h2.x + w3 * h3.x;
        acc.y += w0 * h0.y + w1 * h1.y + w2 * h2.y + w3 * h3.y;
        acc.z += w0 * h0.z + w1 * h1.z + w2 * h2.z + w3 * h3.z;
        acc.w += w0 * h0.w + w1 * h1.w + w2 * h2.w + w3 * h3.w;
    }
    for (; i + 2 <= end; i += 2) {
        int sidx = col[i + half];
        float w = lrelu_exp(asrc[sidx * 4 + head] + ad);
        float4 hv = h16_to_f4(*reinterpret_cast<const uint2*>(h16 + (size_t)sidx * 128 + q * 4));
        s += w;
        acc.x += w * hv.x; acc.y += w * hv.y; acc.z += w * hv.z; acc.w += w * hv.w;
    }
    if (i < end && half == 0) {   // odd remainder: half 0 only
        int sidx = col[i];
        float w = lrelu_exp(asrc[sidx * 4 + head] + ad);
        float4 hv = h16_to_f4(*reinterpret_cast<const uint2*>(h16 + (size_t)sidx * 128 + q * 4));
        s += w;
        acc.x += w * hv.x; acc.y += w * hv.y; acc.z += w * hv.z; acc.w += w * hv.w;
    }

    // combine the two half-wave partials
    s += __shfl_xor(s, 32, 64);
    acc.x += __shfl_xor(acc.x, 32, 64);
    acc.y += __shfl_xor(acc.y, 32, 64);
    acc.z += __shfl_xor(acc.z, 32, 64);
    acc.w += __shfl_xor(acc.w, 32, 64);
    float inv = 1.f / s;
    acc.x *= inv; acc.y *= inv; acc.z *= inv; acc.w *= inv;
    // head mean: lanes q, q^8, q^16, q^24 hold heads 0..3 of channel group q&7
    acc.x += __shfl_xor(acc.x, 8, 64);  acc.x += __shfl_xor(acc.x, 16, 64);
    acc.y += __shfl_xor(acc.y, 8, 64);  acc.y += __shfl_xor(acc.y, 16, 64);
    acc.z += __shfl_xor(acc.z, 8, 64);  acc.z += __shfl_xor(acc.z, 16, 64);
    acc.w += __shfl_xor(acc.w, 8, 64);  acc.w += __shfl_xor(acc.w, 16, 64);
    if (lane < 8) {
        float4 b4 = *reinterpret_cast<const float4*>(&bias[lane * 4]);
        float o0 = acc.x * 0.25f + b4.x;
        float o1 = acc.y * 0.25f + b4.y;
        float o2 = acc.z * 0.25f + b4.z;
        float o3 = acc.w * 0.25f + b4.w;
        o0 = o0 > 0.f ? o0 : (__expf(o0) - 1.f);
        o1 = o1 > 0.f ? o1 : (__expf(o1) - 1.f);
        o2 = o2 > 0.f ? o2 : (__expf(o2) - 1.f);
        o3 = o3 > 0.f ? o3 : (__expf(o3) - 1.f);
        *reinterpret_cast<float4*>(&out[(size_t)wid * 32 + lane * 4]) =
            make_float4(o0, o1, o2, o3);
    }
}

// ---------------- launch ----------------

extern "C" void kernel_launch(void* const* d_in, const int* in_sizes, int n_in,
                              void* d_out, int out_size, void* d_ws, size_t ws_size,
                              hipStream_t stream) {
    const float* x       = (const float*)d_in[0];
    const int*   ei      = (const int*)d_in[1];   // [2,E] int32
    const float* Ws      = (const float*)d_in[3]; // [3,32,128]
    const float* att_src = (const float*)d_in[4]; // [3,4,32]
    const float* att_dst = (const float*)d_in[5];
    const float* bias    = (const float*)d_in[6]; // [3,32]

    int N = in_sizes[0] / 32;
    int E = in_sizes[1] / 2;
    const int* srcv = ei;
    const int* dstv = ei + E;

    // workspace layout
    float* fws   = (float*)d_ws;
    __half* h16  = (__half*)fws;                        // N*128 halves
    float* asrc  = (float*)(h16 + (size_t)N * 128);     // N*4
    float* adst  = asrc + (size_t)N * 4;                // N*4
    float* xbuf  = adst + (size_t)N * 4;                // N*32
    int*   deg    = (int*)(xbuf + (size_t)N * 32);      // N
    int*   rowst  = deg + N;                            // N+1
    int*   cursor = rowst + N + 1;                      // N
    int*   bsums  = cursor + N;                         // 512
    int*   boffs  = bsums + 512;                        // 512
    int*   col    = boffs + 512;                        // E

    int nb256 = (N + 255) / 256;           // <=512 for scan2
    int gemmBlocks = (N + 15) / 16;
    int histBlocks = (E / 4 + 255) / 256 + 1;
    int edgeBlocks4 = (E / 4 + 255) / 256 + 1;

    hipMemsetAsync(deg, 0, (size_t)N * sizeof(int), stream);

    for (int l = 0; l < 3; ++l) {
        const float* xin = (l == 0) ? x : xbuf;
        float* xout = (l == 2) ? (float*)d_out : xbuf;
        int extra = (l == 0) ? histBlocks : 0;
        k_gemm_alpha<<<gemmBlocks + extra, 256, 0, stream>>>(
            xin, Ws + (size_t)l * 32 * 128, att_src + l * 128, att_dst + l * 128,
            h16, asrc, adst, N, dstv, E, deg, gemmBlocks);
        if (l == 0) {
            k_scan1<<<nb256, 256, 0, stream>>>(deg, N, bsums);
            k_scan2<<<1, 512, 0, stream>>>(bsums, nb256, boffs);
            k_scan3<<<nb256, 256, 0, stream>>>(deg, N, boffs, rowst, cursor);
            k_scatter<<<edgeBlocks4, 256, 0, stream>>>(srcv, dstv, E, cursor, col);
        }
        k_agg<<<(N + 3) / 4, 256, 0, stream>>>(
            h16, asrc, adst, rowst, col, bias + l * 32, xout, N);
    }
}

// Round 5
// 527.395 us; speedup vs baseline: 1.6798x; 1.0925x over previous
//
#include <hip/hip_runtime.h>
#include <hip/hip_bf16.h>
#include <hip/hip_fp16.h>
#include <cstdint>

// ---------------- CSR build ----------------

__global__ void k_scan1(const int* __restrict__ deg, int n, int* __restrict__ bsums) {
    __shared__ int s[256];
    int t = threadIdx.x;
    int i = blockIdx.x * 256 + t;
    int v = (i < n) ? deg[i] : 0;
    s[t] = v; __syncthreads();
    for (int off = 128; off > 0; off >>= 1) {
        if (t < off) s[t] += s[t + off];
        __syncthreads();
    }
    if (t == 0) bsums[blockIdx.x] = s[0];
}

// single block, inclusive->exclusive scan of up to 512 block sums
__global__ void k_scan2(const int* __restrict__ bsums, int nb, int* __restrict__ boffs) {
    __shared__ int s[512];
    int t = threadIdx.x;
    int v = (t < nb) ? bsums[t] : 0;
    s[t] = v; __syncthreads();
    for (int off = 1; off < 512; off <<= 1) {
        int nv = (t >= off) ? s[t - off] : 0;
        __syncthreads();
        s[t] += nv;
        __syncthreads();
    }
    if (t < nb) boffs[t] = s[t] - v;  // exclusive
}

__global__ void k_scan3(const int* __restrict__ deg, int n, const int* __restrict__ boffs,
                        int* __restrict__ rowst, int* __restrict__ cursor) {
    __shared__ int s[256];
    int t = threadIdx.x;
    int i = blockIdx.x * 256 + t;
    int v = (i < n) ? deg[i] : 0;
    s[t] = v; __syncthreads();
    for (int off = 1; off < 256; off <<= 1) {
        int nv = (t >= off) ? s[t - off] : 0;
        __syncthreads();
        s[t] += nv;
        __syncthreads();
    }
    int incl = s[t] + boffs[blockIdx.x];
    if (i < n) {
        int ex = incl - v;
        rowst[i] = ex;
        cursor[i] = ex;
        if (i == n - 1) rowst[n] = incl;
    }
}

// 16 edges/thread, three batched phases: loads -> 16 independent atomics -> 16 stores.
__global__ void k_scatter(const int* __restrict__ src, const int* __restrict__ dst, int E,
                          int* __restrict__ cursor, int* __restrict__ col) {
    int t = blockIdx.x * blockDim.x + threadIdx.x;
    int base = t * 16;
    if (base + 16 <= E) {
        int4 d[4], s[4];
#pragma unroll
        for (int k = 0; k < 4; ++k) {
            d[k] = *reinterpret_cast<const int4*>(dst + base + k * 4);
            s[k] = *reinterpret_cast<const int4*>(src + base + k * 4);
        }
        const int* dd = reinterpret_cast<const int*>(d);
        const int* ss = reinterpret_cast<const int*>(s);
        int p[16];
#pragma unroll
        for (int k = 0; k < 16; ++k) p[k] = atomicAdd(&cursor[dd[k]], 1);
#pragma unroll
        for (int k = 0; k < 16; ++k) col[p[k]] = ss[k];
    } else {
        for (int i = base; i < E; ++i) {
            int p = atomicAdd(&cursor[dst[i]], 1);
            col[p] = src[i];
        }
    }
}

// ---------------- per-layer kernels ----------------

// Fused: blocks [0,gemmBlocks) do GEMM+alpha; blocks beyond do the edge histogram
// (layer 0 only). h stored as fp16 (h16), alphas stay fp32.
// GEMM: h = x @ W ([N,32]@[32,128]); 16 nodes per 256-thread block, 1 wave/node.
__global__ void k_gemm_alpha(const float* __restrict__ x, const float* __restrict__ W,
                             const float* __restrict__ a_src, const float* __restrict__ a_dst,
                             __half* __restrict__ h16, float* __restrict__ alpha_src,
                             float* __restrict__ alpha_dst, int n,
                             const int* __restrict__ dstv, int E, int* __restrict__ deg,
                             int gemmBlocks) {
    if ((int)blockIdx.x >= gemmBlocks) {
        int b = blockIdx.x - gemmBlocks;
        int i4 = (b * 256 + threadIdx.x) * 4;
        if (i4 + 4 <= E) {
            int4 d4 = *reinterpret_cast<const int4*>(dstv + i4);
            atomicAdd(&deg[d4.x], 1);
            atomicAdd(&deg[d4.y], 1);
            atomicAdd(&deg[d4.z], 1);
            atomicAdd(&deg[d4.w], 1);
        } else {
            for (int i = i4; i < E; ++i) atomicAdd(&deg[dstv[i]], 1);
        }
        return;
    }
    __shared__ float Wls[32 * 128];
    __shared__ float asl[128], adl[128];
    __shared__ float xs[16][32];
    int t = threadIdx.x;
    for (int i = t; i < 32 * 128; i += 256) Wls[i] = W[i];
    if (t < 128) { asl[t] = a_src[t]; adl[t] = a_dst[t]; }
    int base = blockIdx.x * 16;
    for (int i = t; i < 16 * 32; i += 256) {
        int nn = base + i / 32;
        xs[i / 32][i % 32] = (nn < n) ? x[nn * 32 + i % 32] : 0.f;
    }
    __syncthreads();
    int lane = t & 63;
    int sub = t >> 6;           // wave id within block, 0..3
    int j2 = lane * 2;          // flattened out channel pair = head*32 + c
    for (int p = 0; p < 4; ++p) {
        int local = p * 4 + sub;
        int node = base + local;
        if (node >= n) continue;
        float acc0 = 0.f, acc1 = 0.f;
#pragma unroll
        for (int k = 0; k < 32; ++k) {
            float xv = xs[local][k];
            acc0 += xv * Wls[k * 128 + j2];
            acc1 += xv * Wls[k * 128 + j2 + 1];
        }
        *reinterpret_cast<__half2*>(h16 + (size_t)node * 128 + j2) =
            __floats2half2_rn(acc0, acc1);
        float ps = acc0 * asl[j2] + acc1 * asl[j2 + 1];
        float pd = acc0 * adl[j2] + acc1 * adl[j2 + 1];
#pragma unroll
        for (int m = 1; m < 16; m <<= 1) {
            ps += __shfl_xor(ps, m, 64);
            pd += __shfl_xor(pd, m, 64);
        }
        if ((lane & 15) == 0) {
            int head = lane >> 4;
            alpha_src[node * 4 + head] = ps;
            alpha_dst[node * 4 + head] = pd;
        }
    }
}

__device__ __forceinline__ float lrelu_exp(float e) {
    e = e > 0.f ? e : 0.2f * e;
    return __expf(e);
}

__device__ __forceinline__ float4 h16_to_f4(uint2 v) {
    float2 fa = __half22float2(*reinterpret_cast<__half2*>(&v.x));
    float2 fb = __half22float2(*reinterpret_cast<__half2*>(&v.y));
    return make_float4(fa.x, fa.y, fb.x, fb.y);
}

// one wave per dst node; two edges in flight per gather step (one per half-wave),
// fp16 h rows (256B), uint2 (8B) loads; unroll x4 => 8 edge rows in flight per wave.
// single-pass softmax (no max-shift) + self loop + head-mean + bias + elu.
__global__ void k_agg(const __half* __restrict__ h16, const float* __restrict__ asrc,
                      const float* __restrict__ adst, const int* __restrict__ rowst,
                      const int* __restrict__ col, const float* __restrict__ bias,
                      float* __restrict__ out, int n) {
    int wid = (int)((blockIdx.x * (size_t)blockDim.x + threadIdx.x) >> 6);
    if (wid >= n) return;
    int lane = threadIdx.x & 63;
    int half = lane >> 5;       // which edge of the pair this half-wave handles
    int q = lane & 31;          // channel quad: flattened channels 4q..4q+3
    int head = q >> 3;
    float ad = adst[wid * 4 + head];

    float4 acc = make_float4(0.f, 0.f, 0.f, 0.f);
    float s = 0.f;
    if (half == 0) {  // self loop counted once
        float w = lrelu_exp(asrc[wid * 4 + head] + ad);
        uint2 v = *reinterpret_cast<const uint2*>(h16 + (size_t)wid * 128 + q * 4);
        float4 hv = h16_to_f4(v);
        s = w;
        acc.x = w * hv.x; acc.y = w * hv.y; acc.z = w * hv.z; acc.w = w * hv.w;
    }

    int beg = rowst[wid], end = rowst[wid + 1];
    int i = beg;
    for (; i + 8 <= end; i += 8) {
        int base = i + half * 4;
        int s0 = col[base], s1 = col[base + 1], s2 = col[base + 2], s3 = col[base + 3];
        float x0 = asrc[s0 * 4 + head];
        float x1 = asrc[s1 * 4 + head];
        float x2 = asrc[s2 * 4 + head];
        float x3 = asrc[s3 * 4 + head];
        uint2 v0 = *reinterpret_cast<const uint2*>(h16 + (size_t)s0 * 128 + q * 4);
        uint2 v1 = *reinterpret_cast<const uint2*>(h16 + (size_t)s1 * 128 + q * 4);
        uint2 v2 = *reinterpret_cast<const uint2*>(h16 + (size_t)s2 * 128 + q * 4);
        uint2 v3 = *reinterpret_cast<const uint2*>(h16 + (size_t)s3 * 128 + q * 4);
        float w0 = lrelu_exp(x0 + ad);
        float w1 = lrelu_exp(x1 + ad);
        float w2 = lrelu_exp(x2 + ad);
        float w3 = lrelu_exp(x3 + ad);
        float4 h0 = h16_to_f4(v0), h1 = h16_to_f4(v1), h2 = h16_to_f4(v2), h3 = h16_to_f4(v3);
        s += w0 + w1 + w2 + w3;
        acc.x += w0 * h0.x + w1 * h1.x + w2 * h2.x + w3 * h3.x;
        acc.y += w0 * h0.y + w1 * h1.y + w2 * h2.y + w3 * h3.y;
        acc.z += w0 * h0.z + w1 * h1.z + w2 * h2.z + w3 * h3.z;
        acc.w += w0 * h0.w + w1 * h1.w + w2 * h2.w + w3 * h3.w;
    }
    for (; i + 2 <= end; i += 2) {
        int sidx = col[i + half];
        float w = lrelu_exp(asrc[sidx * 4 + head] + ad);
        float4 hv = h16_to_f4(*reinterpret_cast<const uint2*>(h16 + (size_t)sidx * 128 + q * 4));
        s += w;
        acc.x += w * hv.x; acc.y += w * hv.y; acc.z += w * hv.z; acc.w += w * hv.w;
    }
    if (i < end && half == 0) {   // odd remainder: half 0 only
        int sidx = col[i];
        float w = lrelu_exp(asrc[sidx * 4 + head] + ad);
        float4 hv = h16_to_f4(*reinterpret_cast<const uint2*>(h16 + (size_t)sidx * 128 + q * 4));
        s += w;
        acc.x += w * hv.x; acc.y += w * hv.y; acc.z += w * hv.z; acc.w += w * hv.w;
    }

    // combine the two half-wave partials
    s += __shfl_xor(s, 32, 64);
    acc.x += __shfl_xor(acc.x, 32, 64);
    acc.y += __shfl_xor(acc.y, 32, 64);
    acc.z += __shfl_xor(acc.z, 32, 64);
    acc.w += __shfl_xor(acc.w, 32, 64);
    float inv = 1.f / s;
    acc.x *= inv; acc.y *= inv; acc.z *= inv; acc.w *= inv;
    // head mean: lanes q, q^8, q^16, q^24 hold heads 0..3 of channel group q&7
    acc.x += __shfl_xor(acc.x, 8, 64);  acc.x += __shfl_xor(acc.x, 16, 64);
    acc.y += __shfl_xor(acc.y, 8, 64);  acc.y += __shfl_xor(acc.y, 16, 64);
    acc.z += __shfl_xor(acc.z, 8, 64);  acc.z += __shfl_xor(acc.z, 16, 64);
    acc.w += __shfl_xor(acc.w, 8, 64);  acc.w += __shfl_xor(acc.w, 16, 64);
    if (lane < 8) {
        float4 b4 = *reinterpret_cast<const float4*>(&bias[lane * 4]);
        float o0 = acc.x * 0.25f + b4.x;
        float o1 = acc.y * 0.25f + b4.y;
        float o2 = acc.z * 0.25f + b4.z;
        float o3 = acc.w * 0.25f + b4.w;
        o0 = o0 > 0.f ? o0 : (__expf(o0) - 1.f);
        o1 = o1 > 0.f ? o1 : (__expf(o1) - 1.f);
        o2 = o2 > 0.f ? o2 : (__expf(o2) - 1.f);
        o3 = o3 > 0.f ? o3 : (__expf(o3) - 1.f);
        *reinterpret_cast<float4*>(&out[(size_t)wid * 32 + lane * 4]) =
            make_float4(o0, o1, o2, o3);
    }
}

// ---------------- launch ----------------

extern "C" void kernel_launch(void* const* d_in, const int* in_sizes, int n_in,
                              void* d_out, int out_size, void* d_ws, size_t ws_size,
                              hipStream_t stream) {
    const float* x       = (const float*)d_in[0];
    const int*   ei      = (const int*)d_in[1];   // [2,E] int32
    const float* Ws      = (const float*)d_in[3]; // [3,32,128]
    const float* att_src = (const float*)d_in[4]; // [3,4,32]
    const float* att_dst = (const float*)d_in[5];
    const float* bias    = (const float*)d_in[6]; // [3,32]

    int N = in_sizes[0] / 32;
    int E = in_sizes[1] / 2;
    const int* srcv = ei;
    const int* dstv = ei + E;

    // workspace layout
    float* fws   = (float*)d_ws;
    __half* h16  = (__half*)fws;                        // N*128 halves
    float* asrc  = (float*)(h16 + (size_t)N * 128);     // N*4
    float* adst  = asrc + (size_t)N * 4;                // N*4
    float* xbuf  = adst + (size_t)N * 4;                // N*32
    int*   deg    = (int*)(xbuf + (size_t)N * 32);      // N
    int*   rowst  = deg + N;                            // N+1
    int*   cursor = rowst + N + 1;                      // N
    int*   bsums  = cursor + N;                         // 512
    int*   boffs  = bsums + 512;                        // 512
    int*   col    = boffs + 512;                        // E

    int nb256 = (N + 255) / 256;           // <=512 for scan2
    int gemmBlocks = (N + 15) / 16;
    int histBlocks = (E / 4 + 255) / 256 + 1;
    int scatBlocks = (E + 16 * 256 - 1) / (16 * 256);

    hipMemsetAsync(deg, 0, (size_t)N * sizeof(int), stream);

    for (int l = 0; l < 3; ++l) {
        const float* xin = (l == 0) ? x : xbuf;
        float* xout = (l == 2) ? (float*)d_out : xbuf;
        int extra = (l == 0) ? histBlocks : 0;
        k_gemm_alpha<<<gemmBlocks + extra, 256, 0, stream>>>(
            xin, Ws + (size_t)l * 32 * 128, att_src + l * 128, att_dst + l * 128,
            h16, asrc, adst, N, dstv, E, deg, gemmBlocks);
        if (l == 0) {
            k_scan1<<<nb256, 256, 0, stream>>>(deg, N, bsums);
            k_scan2<<<1, 512, 0, stream>>>(bsums, nb256, boffs);
            k_scan3<<<nb256, 256, 0, stream>>>(deg, N, boffs, rowst, cursor);
            k_scatter<<<scatBlocks, 256, 0, stream>>>(srcv, dstv, E, cursor, col);
        }
        k_agg<<<(N + 3) / 4, 256, 0, stream>>>(
            h16, asrc, adst, rowst, col, bias + l * 32, xout, N);
    }
}

// Round 6
// 493.253 us; speedup vs baseline: 1.7961x; 1.0692x over previous
//
#include <hip/hip_runtime.h>
#include <hip/hip_bf16.h>
#include <hip/hip_fp16.h>
#include <cstdint>

// ---------------- CSR build ----------------

__global__ void k_scan1(const int* __restrict__ deg, int n, int* __restrict__ bsums) {
    __shared__ int s[256];
    int t = threadIdx.x;
    int i = blockIdx.x * 256 + t;
    int v = (i < n) ? deg[i] : 0;
    s[t] = v; __syncthreads();
    for (int off = 128; off > 0; off >>= 1) {
        if (t < off) s[t] += s[t + off];
        __syncthreads();
    }
    if (t == 0) bsums[blockIdx.x] = s[0];
}

// single block, inclusive->exclusive scan of up to 512 block sums
__global__ void k_scan2(const int* __restrict__ bsums, int nb, int* __restrict__ boffs) {
    __shared__ int s[512];
    int t = threadIdx.x;
    int v = (t < nb) ? bsums[t] : 0;
    s[t] = v; __syncthreads();
    for (int off = 1; off < 512; off <<= 1) {
        int nv = (t >= off) ? s[t - off] : 0;
        __syncthreads();
        s[t] += nv;
        __syncthreads();
    }
    if (t < nb) boffs[t] = s[t] - v;  // exclusive
}

__global__ void k_scan3(const int* __restrict__ deg, int n, const int* __restrict__ boffs,
                        int* __restrict__ rowst, int* __restrict__ cursor) {
    __shared__ int s[256];
    int t = threadIdx.x;
    int i = blockIdx.x * 256 + t;
    int v = (i < n) ? deg[i] : 0;
    s[t] = v; __syncthreads();
    for (int off = 1; off < 256; off <<= 1) {
        int nv = (t >= off) ? s[t - off] : 0;
        __syncthreads();
        s[t] += nv;
        __syncthreads();
    }
    int incl = s[t] + boffs[blockIdx.x];
    if (i < n) {
        int ex = incl - v;
        rowst[i] = ex;
        cursor[i] = ex;
        if (i == n - 1) rowst[n] = incl;
    }
}

// 16 edges/thread, three batched phases: loads -> 16 independent atomics -> 16 stores.
__global__ void k_scatter(const int* __restrict__ src, const int* __restrict__ dst, int E,
                          int* __restrict__ cursor, int* __restrict__ col) {
    int t = blockIdx.x * blockDim.x + threadIdx.x;
    int base = t * 16;
    if (base + 16 <= E) {
        int4 d[4], s[4];
#pragma unroll
        for (int k = 0; k < 4; ++k) {
            d[k] = *reinterpret_cast<const int4*>(dst + base + k * 4);
            s[k] = *reinterpret_cast<const int4*>(src + base + k * 4);
        }
        const int* dd = reinterpret_cast<const int*>(d);
        const int* ss = reinterpret_cast<const int*>(s);
        int p[16];
#pragma unroll
        for (int k = 0; k < 16; ++k) p[k] = atomicAdd(&cursor[dd[k]], 1);
#pragma unroll
        for (int k = 0; k < 16; ++k) col[p[k]] = ss[k];
    } else {
        for (int i = base; i < E; ++i) {
            int p = atomicAdd(&cursor[dst[i]], 1);
            col[p] = src[i];
        }
    }
}

// ---------------- per-layer kernels ----------------

__device__ __forceinline__ float lane_bcast(float v, int k) {
    return __int_as_float(__builtin_amdgcn_readlane(__float_as_int(v), k));
}

// Fused: blocks [0,gemmBlocks) do GEMM+alpha; blocks beyond do the edge histogram
// (layer 0 only).  Zero-LDS GEMM: each wave owns 16 nodes; lane holds W column
// pair in 64 VGPRs; x broadcast via readlane (static index, fully unrolled).
__global__ void __launch_bounds__(256)
k_gemm_alpha(const float* __restrict__ x, const float* __restrict__ W,
             const float* __restrict__ a_src, const float* __restrict__ a_dst,
             __half* __restrict__ h16, float* __restrict__ alpha_src,
             float* __restrict__ alpha_dst, int n,
             const int* __restrict__ dstv, int E, int* __restrict__ deg,
             int gemmBlocks) {
    if ((int)blockIdx.x >= gemmBlocks) {
        // 16 edges/thread histogram (atomics are fire-and-forget; batch the loads)
        int b = blockIdx.x - gemmBlocks;
        int base = (b * 256 + threadIdx.x) * 16;
        if (base + 16 <= E) {
            int4 d[4];
#pragma unroll
            for (int k = 0; k < 4; ++k)
                d[k] = *reinterpret_cast<const int4*>(dstv + base + k * 4);
            const int* dd = reinterpret_cast<const int*>(d);
#pragma unroll
            for (int k = 0; k < 16; ++k) atomicAdd(&deg[dd[k]], 1);
        } else {
            for (int i = base; i < E; ++i) atomicAdd(&deg[dstv[i]], 1);
        }
        return;
    }
    int lane = threadIdx.x & 63;
    int wave = threadIdx.x >> 6;
    int j2 = lane * 2;              // flattened out channel pair = head*32 + c
    int nbase = blockIdx.x * 64 + wave * 16;

    // W column pair -> 64 VGPRs (32 x float2); att vectors -> 4 regs
    float2 wr[32];
#pragma unroll
    for (int k = 0; k < 32; ++k)
        wr[k] = *reinterpret_cast<const float2*>(W + k * 128 + j2);
    float2 as2 = *reinterpret_cast<const float2*>(a_src + j2);
    float2 ad2 = *reinterpret_cast<const float2*>(a_dst + j2);

    // x rows for the 16 nodes: one VGPR each (lane&31 -> channel)
    float xr[16];
#pragma unroll
    for (int m = 0; m < 16; ++m) {
        int node = nbase + m;
        xr[m] = (node < n) ? x[(size_t)node * 32 + (lane & 31)] : 0.f;
    }

#pragma unroll
    for (int m = 0; m < 16; ++m) {
        int node = nbase + m;
        if (node >= n) continue;     // wave-uniform guard
        float acc0 = 0.f, acc1 = 0.f;
#pragma unroll
        for (int k = 0; k < 32; ++k) {
            float xv = lane_bcast(xr[m], k);      // x[node][k] via readlane (SGPR)
            acc0 += xv * wr[k].x;
            acc1 += xv * wr[k].y;
        }
        *reinterpret_cast<__half2*>(h16 + (size_t)node * 128 + j2) =
            __floats2half2_rn(acc0, acc1);
        float ps = acc0 * as2.x + acc1 * as2.y;
        float pd = acc0 * ad2.x + acc1 * ad2.y;
#pragma unroll
        for (int mm = 1; mm < 16; mm <<= 1) {
            ps += __shfl_xor(ps, mm, 64);
            pd += __shfl_xor(pd, mm, 64);
        }
        if ((lane & 15) == 0) {
            int head = lane >> 4;
            alpha_src[node * 4 + head] = ps;
            alpha_dst[node * 4 + head] = pd;
        }
    }
}

__device__ __forceinline__ float lrelu_exp(float e) {
    e = e > 0.f ? e : 0.2f * e;
    return __expf(e);
}

__device__ __forceinline__ float4 h16_to_f4(uint2 v) {
    float2 fa = __half22float2(*reinterpret_cast<__half2*>(&v.x));
    float2 fb = __half22float2(*reinterpret_cast<__half2*>(&v.y));
    return make_float4(fa.x, fa.y, fb.x, fb.y);
}

// one wave per dst node; two edges in flight per gather step (one per half-wave),
// fp16 h rows (256B), uint2 (8B) loads; unroll x4 => 8 edge rows in flight per wave.
// single-pass softmax (no max-shift) + self loop + head-mean + bias + elu.
__global__ void k_agg(const __half* __restrict__ h16, const float* __restrict__ asrc,
                      const float* __restrict__ adst, const int* __restrict__ rowst,
                      const int* __restrict__ col, const float* __restrict__ bias,
                      float* __restrict__ out, int n) {
    int wid = (int)((blockIdx.x * (size_t)blockDim.x + threadIdx.x) >> 6);
    if (wid >= n) return;
    int lane = threadIdx.x & 63;
    int half = lane >> 5;       // which edge of the pair this half-wave handles
    int q = lane & 31;          // channel quad: flattened channels 4q..4q+3
    int head = q >> 3;
    float ad = adst[wid * 4 + head];

    float4 acc = make_float4(0.f, 0.f, 0.f, 0.f);
    float s = 0.f;
    if (half == 0) {  // self loop counted once
        float w = lrelu_exp(asrc[wid * 4 + head] + ad);
        uint2 v = *reinterpret_cast<const uint2*>(h16 + (size_t)wid * 128 + q * 4);
        float4 hv = h16_to_f4(v);
        s = w;
        acc.x = w * hv.x; acc.y = w * hv.y; acc.z = w * hv.z; acc.w = w * hv.w;
    }

    int beg = rowst[wid], end = rowst[wid + 1];
    int i = beg;
    for (; i + 8 <= end; i += 8) {
        int base = i + half * 4;
        int s0 = col[base], s1 = col[base + 1], s2 = col[base + 2], s3 = col[base + 3];
        float x0 = asrc[s0 * 4 + head];
        float x1 = asrc[s1 * 4 + head];
        float x2 = asrc[s2 * 4 + head];
        float x3 = asrc[s3 * 4 + head];
        uint2 v0 = *reinterpret_cast<const uint2*>(h16 + (size_t)s0 * 128 + q * 4);
        uint2 v1 = *reinterpret_cast<const uint2*>(h16 + (size_t)s1 * 128 + q * 4);
        uint2 v2 = *reinterpret_cast<const uint2*>(h16 + (size_t)s2 * 128 + q * 4);
        uint2 v3 = *reinterpret_cast<const uint2*>(h16 + (size_t)s3 * 128 + q * 4);
        float w0 = lrelu_exp(x0 + ad);
        float w1 = lrelu_exp(x1 + ad);
        float w2 = lrelu_exp(x2 + ad);
        float w3 = lrelu_exp(x3 + ad);
        float4 h0 = h16_to_f4(v0), h1 = h16_to_f4(v1), h2 = h16_to_f4(v2), h3 = h16_to_f4(v3);
        s += w0 + w1 + w2 + w3;
        acc.x += w0 * h0.x + w1 * h1.x + w2 * h2.x + w3 * h3.x;
        acc.y += w0 * h0.y + w1 * h1.y + w2 * h2.y + w3 * h3.y;
        acc.z += w0 * h0.z + w1 * h1.z + w2 * h2.z + w3 * h3.z;
        acc.w += w0 * h0.w + w1 * h1.w + w2 * h2.w + w3 * h3.w;
    }
    for (; i + 2 <= end; i += 2) {
        int sidx = col[i + half];
        float w = lrelu_exp(asrc[sidx * 4 + head] + ad);
        float4 hv = h16_to_f4(*reinterpret_cast<const uint2*>(h16 + (size_t)sidx * 128 + q * 4));
        s += w;
        acc.x += w * hv.x; acc.y += w * hv.y; acc.z += w * hv.z; acc.w += w * hv.w;
    }
    if (i < end && half == 0) {   // odd remainder: half 0 only
        int sidx = col[i];
        float w = lrelu_exp(asrc[sidx * 4 + head] + ad);
        float4 hv = h16_to_f4(*reinterpret_cast<const uint2*>(h16 + (size_t)sidx * 128 + q * 4));
        s += w;
        acc.x += w * hv.x; acc.y += w * hv.y; acc.z += w * hv.z; acc.w += w * hv.w;
    }

    // combine the two half-wave partials
    s += __shfl_xor(s, 32, 64);
    acc.x += __shfl_xor(acc.x, 32, 64);
    acc.y += __shfl_xor(acc.y, 32, 64);
    acc.z += __shfl_xor(acc.z, 32, 64);
    acc.w += __shfl_xor(acc.w, 32, 64);
    float inv = 1.f / s;
    acc.x *= inv; acc.y *= inv; acc.z *= inv; acc.w *= inv;
    // head mean: lanes q, q^8, q^16, q^24 hold heads 0..3 of channel group q&7
    acc.x += __shfl_xor(acc.x, 8, 64);  acc.x += __shfl_xor(acc.x, 16, 64);
    acc.y += __shfl_xor(acc.y, 8, 64);  acc.y += __shfl_xor(acc.y, 16, 64);
    acc.z += __shfl_xor(acc.z, 8, 64);  acc.z += __shfl_xor(acc.z, 16, 64);
    acc.w += __shfl_xor(acc.w, 8, 64);  acc.w += __shfl_xor(acc.w, 16, 64);
    if (lane < 8) {
        float4 b4 = *reinterpret_cast<const float4*>(&bias[lane * 4]);
        float o0 = acc.x * 0.25f + b4.x;
        float o1 = acc.y * 0.25f + b4.y;
        float o2 = acc.z * 0.25f + b4.z;
        float o3 = acc.w * 0.25f + b4.w;
        o0 = o0 > 0.f ? o0 : (__expf(o0) - 1.f);
        o1 = o1 > 0.f ? o1 : (__expf(o1) - 1.f);
        o2 = o2 > 0.f ? o2 : (__expf(o2) - 1.f);
        o3 = o3 > 0.f ? o3 : (__expf(o3) - 1.f);
        *reinterpret_cast<float4*>(&out[(size_t)wid * 32 + lane * 4]) =
            make_float4(o0, o1, o2, o3);
    }
}

// ---------------- launch ----------------

extern "C" void kernel_launch(void* const* d_in, const int* in_sizes, int n_in,
                              void* d_out, int out_size, void* d_ws, size_t ws_size,
                              hipStream_t stream) {
    const float* x       = (const float*)d_in[0];
    const int*   ei      = (const int*)d_in[1];   // [2,E] int32
    const float* Ws      = (const float*)d_in[3]; // [3,32,128]
    const float* att_src = (const float*)d_in[4]; // [3,4,32]
    const float* att_dst = (const float*)d_in[5];
    const float* bias    = (const float*)d_in[6]; // [3,32]

    int N = in_sizes[0] / 32;
    int E = in_sizes[1] / 2;
    const int* srcv = ei;
    const int* dstv = ei + E;

    // workspace layout
    float* fws   = (float*)d_ws;
    __half* h16  = (__half*)fws;                        // N*128 halves
    float* asrc  = (float*)(h16 + (size_t)N * 128);     // N*4
    float* adst  = asrc + (size_t)N * 4;                // N*4
    float* xbuf  = adst + (size_t)N * 4;                // N*32
    int*   deg    = (int*)(xbuf + (size_t)N * 32);      // N
    int*   rowst  = deg + N;                            // N+1
    int*   cursor = rowst + N + 1;                      // N
    int*   bsums  = cursor + N;                         // 512
    int*   boffs  = bsums + 512;                        // 512
    int*   col    = boffs + 512;                        // E

    int nb256 = (N + 255) / 256;           // <=512 for scan2
    int gemmBlocks = (N + 63) / 64;
    int histBlocks = (E + 16 * 256 - 1) / (16 * 256);
    int scatBlocks = (E + 16 * 256 - 1) / (16 * 256);

    hipMemsetAsync(deg, 0, (size_t)N * sizeof(int), stream);

    for (int l = 0; l < 3; ++l) {
        const float* xin = (l == 0) ? x : xbuf;
        float* xout = (l == 2) ? (float*)d_out : xbuf;
        int extra = (l == 0) ? histBlocks : 0;
        k_gemm_alpha<<<gemmBlocks + extra, 256, 0, stream>>>(
            xin, Ws + (size_t)l * 32 * 128, att_src + l * 128, att_dst + l * 128,
            h16, asrc, adst, N, dstv, E, deg, gemmBlocks);
        if (l == 0) {
            k_scan1<<<nb256, 256, 0, stream>>>(deg, N, bsums);
            k_scan2<<<1, 512, 0, stream>>>(bsums, nb256, boffs);
            k_scan3<<<nb256, 256, 0, stream>>>(deg, N, boffs, rowst, cursor);
            k_scatter<<<scatBlocks, 256, 0, stream>>>(srcv, dstv, E, cursor, col);
        }
        k_agg<<<(N + 3) / 4, 256, 0, stream>>>(
            h16, asrc, adst, rowst, col, bias + l * 32, xout, N);
    }
}

// Round 7
// 448.074 us; speedup vs baseline: 1.9772x; 1.1008x over previous
//
#include <hip/hip_runtime.h>
#include <hip/hip_bf16.h>
#include <hip/hip_fp16.h>
#include <cstdint>

// ---------------- CSR build ----------------

__global__ void k_scan1(const int* __restrict__ deg, int n, int* __restrict__ bsums) {
    __shared__ int s[256];
    int t = threadIdx.x;
    int i = blockIdx.x * 256 + t;
    int v = (i < n) ? deg[i] : 0;
    s[t] = v; __syncthreads();
    for (int off = 128; off > 0; off >>= 1) {
        if (t < off) s[t] += s[t + off];
        __syncthreads();
    }
    if (t == 0) bsums[blockIdx.x] = s[0];
}

// single block, inclusive->exclusive scan of up to 512 block sums
__global__ void k_scan2(const int* __restrict__ bsums, int nb, int* __restrict__ boffs) {
    __shared__ int s[512];
    int t = threadIdx.x;
    int v = (t < nb) ? bsums[t] : 0;
    s[t] = v; __syncthreads();
    for (int off = 1; off < 512; off <<= 1) {
        int nv = (t >= off) ? s[t - off] : 0;
        __syncthreads();
        s[t] += nv;
        __syncthreads();
    }
    if (t < nb) boffs[t] = s[t] - v;  // exclusive
}

__global__ void k_scan3(const int* __restrict__ deg, int n, const int* __restrict__ boffs,
                        int* __restrict__ rowst) {
    __shared__ int s[256];
    int t = threadIdx.x;
    int i = blockIdx.x * 256 + t;
    int v = (i < n) ? deg[i] : 0;
    s[t] = v; __syncthreads();
    for (int off = 1; off < 256; off <<= 1) {
        int nv = (t >= off) ? s[t - off] : 0;
        __syncthreads();
        s[t] += nv;
        __syncthreads();
    }
    int incl = s[t] + boffs[blockIdx.x];
    if (i < n) {
        rowst[i] = incl - v;
        if (i == n - 1) rowst[n] = incl;
    }
}

// atomic-free scatter: position = rowst[dst] + rank (rank captured during hist).
// 8 edges/thread; all loads/stores independent -> deep MLP.
__global__ void k_scatter(const int* __restrict__ src, const int* __restrict__ dst,
                          const int* __restrict__ rank, const int* __restrict__ rowst,
                          int E, int* __restrict__ col) {
    int t = blockIdx.x * blockDim.x + threadIdx.x;
    int base = t * 8;
    if (base + 8 <= E) {
        int4 d[2], s[2], r[2];
#pragma unroll
        for (int k = 0; k < 2; ++k) {
            d[k] = *reinterpret_cast<const int4*>(dst + base + k * 4);
            s[k] = *reinterpret_cast<const int4*>(src + base + k * 4);
            r[k] = *reinterpret_cast<const int4*>(rank + base + k * 4);
        }
        const int* dd = reinterpret_cast<const int*>(d);
        const int* ss = reinterpret_cast<const int*>(s);
        const int* rr = reinterpret_cast<const int*>(r);
        int p[8];
#pragma unroll
        for (int k = 0; k < 8; ++k) p[k] = rowst[dd[k]] + rr[k];
#pragma unroll
        for (int k = 0; k < 8; ++k) col[p[k]] = ss[k];
    } else {
        for (int i = base; i < E; ++i) col[rowst[dst[i]] + rank[i]] = src[i];
    }
}

// ---------------- per-layer kernels ----------------

__device__ __forceinline__ float lane_bcast(float v, int k) {
    return __int_as_float(__builtin_amdgcn_readlane(__float_as_int(v), k));
}

// Fused: blocks [0,gemmBlocks) do GEMM+alpha; blocks beyond do the edge histogram
// AND capture each edge's rank within its dst segment (layer 0 only).
// Zero-LDS GEMM: each wave owns 16 nodes; lane holds W column pair in 64 VGPRs;
// x broadcast via readlane (static index, fully unrolled).
__global__ void __launch_bounds__(256)
k_gemm_alpha(const float* __restrict__ x, const float* __restrict__ W,
             const float* __restrict__ a_src, const float* __restrict__ a_dst,
             __half* __restrict__ h16, float* __restrict__ alpha_src,
             float* __restrict__ alpha_dst, int n,
             const int* __restrict__ dstv, int E, int* __restrict__ deg,
             int* __restrict__ rank, int gemmBlocks) {
    if ((int)blockIdx.x >= gemmBlocks) {
        // 8 edges/thread histogram; atomic return value = rank within dst segment
        int b = blockIdx.x - gemmBlocks;
        int base = (b * 256 + threadIdx.x) * 8;
        if (base + 8 <= E) {
            int4 d[2];
#pragma unroll
            for (int k = 0; k < 2; ++k)
                d[k] = *reinterpret_cast<const int4*>(dstv + base + k * 4);
            const int* dd = reinterpret_cast<const int*>(d);
            int r[8];
#pragma unroll
            for (int k = 0; k < 8; ++k) r[k] = atomicAdd(&deg[dd[k]], 1);
#pragma unroll
            for (int k = 0; k < 2; ++k)
                *reinterpret_cast<int4*>(rank + base + k * 4) =
                    *reinterpret_cast<const int4*>(r + k * 4);
        } else {
            for (int i = base; i < E; ++i) rank[i] = atomicAdd(&deg[dstv[i]], 1);
        }
        return;
    }
    int lane = threadIdx.x & 63;
    int wave = threadIdx.x >> 6;
    int j2 = lane * 2;              // flattened out channel pair = head*32 + c
    int nbase = blockIdx.x * 64 + wave * 16;

    // W column pair -> 64 VGPRs (32 x float2); att vectors -> 4 regs
    float2 wr[32];
#pragma unroll
    for (int k = 0; k < 32; ++k)
        wr[k] = *reinterpret_cast<const float2*>(W + k * 128 + j2);
    float2 as2 = *reinterpret_cast<const float2*>(a_src + j2);
    float2 ad2 = *reinterpret_cast<const float2*>(a_dst + j2);

    // x rows for the 16 nodes: one VGPR each (lane&31 -> channel)
    float xr[16];
#pragma unroll
    for (int m = 0; m < 16; ++m) {
        int node = nbase + m;
        xr[m] = (node < n) ? x[(size_t)node * 32 + (lane & 31)] : 0.f;
    }

#pragma unroll
    for (int m = 0; m < 16; ++m) {
        int node = nbase + m;
        if (node >= n) continue;     // wave-uniform guard
        float acc0 = 0.f, acc1 = 0.f;
#pragma unroll
        for (int k = 0; k < 32; ++k) {
            float xv = lane_bcast(xr[m], k);      // x[node][k] via readlane (SGPR)
            acc0 += xv * wr[k].x;
            acc1 += xv * wr[k].y;
        }
        *reinterpret_cast<__half2*>(h16 + (size_t)node * 128 + j2) =
            __floats2half2_rn(acc0, acc1);
        float ps = acc0 * as2.x + acc1 * as2.y;
        float pd = acc0 * ad2.x + acc1 * ad2.y;
#pragma unroll
        for (int mm = 1; mm < 16; mm <<= 1) {
            ps += __shfl_xor(ps, mm, 64);
            pd += __shfl_xor(pd, mm, 64);
        }
        if ((lane & 15) == 0) {
            int head = lane >> 4;
            alpha_src[node * 4 + head] = ps;
            alpha_dst[node * 4 + head] = pd;
        }
    }
}

__device__ __forceinline__ float lrelu_exp(float e) {
    e = e > 0.f ? e : 0.2f * e;
    return __expf(e);
}

__device__ __forceinline__ float4 h16_to_f4(uint2 v) {
    float2 fa = __half22float2(*reinterpret_cast<__half2*>(&v.x));
    float2 fb = __half22float2(*reinterpret_cast<__half2*>(&v.y));
    return make_float4(fa.x, fa.y, fb.x, fb.y);
}

// one wave per dst node; two edges in flight per gather step (one per half-wave),
// fp16 h rows (256B), uint2 (8B) loads; unroll x4 => 8 edge rows in flight per wave.
// single-pass softmax (no max-shift) + self loop + head-mean + bias + elu.
__global__ void k_agg(const __half* __restrict__ h16, const float* __restrict__ asrc,
                      const float* __restrict__ adst, const int* __restrict__ rowst,
                      const int* __restrict__ col, const float* __restrict__ bias,
                      float* __restrict__ out, int n) {
    int wid = (int)((blockIdx.x * (size_t)blockDim.x + threadIdx.x) >> 6);
    if (wid >= n) return;
    int lane = threadIdx.x & 63;
    int half = lane >> 5;       // which edge of the pair this half-wave handles
    int q = lane & 31;          // channel quad: flattened channels 4q..4q+3
    int head = q >> 3;
    float ad = adst[wid * 4 + head];

    float4 acc = make_float4(0.f, 0.f, 0.f, 0.f);
    float s = 0.f;
    if (half == 0) {  // self loop counted once
        float w = lrelu_exp(asrc[wid * 4 + head] + ad);
        uint2 v = *reinterpret_cast<const uint2*>(h16 + (size_t)wid * 128 + q * 4);
        float4 hv = h16_to_f4(v);
        s = w;
        acc.x = w * hv.x; acc.y = w * hv.y; acc.z = w * hv.z; acc.w = w * hv.w;
    }

    int beg = rowst[wid], end = rowst[wid + 1];
    int i = beg;
    for (; i + 8 <= end; i += 8) {
        int base = i + half * 4;
        int s0 = col[base], s1 = col[base + 1], s2 = col[base + 2], s3 = col[base + 3];
        float x0 = asrc[s0 * 4 + head];
        float x1 = asrc[s1 * 4 + head];
        float x2 = asrc[s2 * 4 + head];
        float x3 = asrc[s3 * 4 + head];
        uint2 v0 = *reinterpret_cast<const uint2*>(h16 + (size_t)s0 * 128 + q * 4);
        uint2 v1 = *reinterpret_cast<const uint2*>(h16 + (size_t)s1 * 128 + q * 4);
        uint2 v2 = *reinterpret_cast<const uint2*>(h16 + (size_t)s2 * 128 + q * 4);
        uint2 v3 = *reinterpret_cast<const uint2*>(h16 + (size_t)s3 * 128 + q * 4);
        float w0 = lrelu_exp(x0 + ad);
        float w1 = lrelu_exp(x1 + ad);
        float w2 = lrelu_exp(x2 + ad);
        float w3 = lrelu_exp(x3 + ad);
        float4 h0 = h16_to_f4(v0), h1 = h16_to_f4(v1), h2 = h16_to_f4(v2), h3 = h16_to_f4(v3);
        s += w0 + w1 + w2 + w3;
        acc.x += w0 * h0.x + w1 * h1.x + w2 * h2.x + w3 * h3.x;
        acc.y += w0 * h0.y + w1 * h1.y + w2 * h2.y + w3 * h3.y;
        acc.z += w0 * h0.z + w1 * h1.z + w2 * h2.z + w3 * h3.z;
        acc.w += w0 * h0.w + w1 * h1.w + w2 * h2.w + w3 * h3.w;
    }
    for (; i + 2 <= end; i += 2) {
        int sidx = col[i + half];
        float w = lrelu_exp(asrc[sidx * 4 + head] + ad);
        float4 hv = h16_to_f4(*reinterpret_cast<const uint2*>(h16 + (size_t)sidx * 128 + q * 4));
        s += w;
        acc.x += w * hv.x; acc.y += w * hv.y; acc.z += w * hv.z; acc.w += w * hv.w;
    }
    if (i < end && half == 0) {   // odd remainder: half 0 only
        int sidx = col[i];
        float w = lrelu_exp(asrc[sidx * 4 + head] + ad);
        float4 hv = h16_to_f4(*reinterpret_cast<const uint2*>(h16 + (size_t)sidx * 128 + q * 4));
        s += w;
        acc.x += w * hv.x; acc.y += w * hv.y; acc.z += w * hv.z; acc.w += w * hv.w;
    }

    // combine the two half-wave partials
    s += __shfl_xor(s, 32, 64);
    acc.x += __shfl_xor(acc.x, 32, 64);
    acc.y += __shfl_xor(acc.y, 32, 64);
    acc.z += __shfl_xor(acc.z, 32, 64);
    acc.w += __shfl_xor(acc.w, 32, 64);
    float inv = 1.f / s;
    acc.x *= inv; acc.y *= inv; acc.z *= inv; acc.w *= inv;
    // head mean: lanes q, q^8, q^16, q^24 hold heads 0..3 of channel group q&7
    acc.x += __shfl_xor(acc.x, 8, 64);  acc.x += __shfl_xor(acc.x, 16, 64);
    acc.y += __shfl_xor(acc.y, 8, 64);  acc.y += __shfl_xor(acc.y, 16, 64);
    acc.z += __shfl_xor(acc.z, 8, 64);  acc.z += __shfl_xor(acc.z, 16, 64);
    acc.w += __shfl_xor(acc.w, 8, 64);  acc.w += __shfl_xor(acc.w, 16, 64);
    if (lane < 8) {
        float4 b4 = *reinterpret_cast<const float4*>(&bias[lane * 4]);
        float o0 = acc.x * 0.25f + b4.x;
        float o1 = acc.y * 0.25f + b4.y;
        float o2 = acc.z * 0.25f + b4.z;
        float o3 = acc.w * 0.25f + b4.w;
        o0 = o0 > 0.f ? o0 : (__expf(o0) - 1.f);
        o1 = o1 > 0.f ? o1 : (__expf(o1) - 1.f);
        o2 = o2 > 0.f ? o2 : (__expf(o2) - 1.f);
        o3 = o3 > 0.f ? o3 : (__expf(o3) - 1.f);
        *reinterpret_cast<float4*>(&out[(size_t)wid * 32 + lane * 4]) =
            make_float4(o0, o1, o2, o3);
    }
}

// ---------------- launch ----------------

extern "C" void kernel_launch(void* const* d_in, const int* in_sizes, int n_in,
                              void* d_out, int out_size, void* d_ws, size_t ws_size,
                              hipStream_t stream) {
    const float* x       = (const float*)d_in[0];
    const int*   ei      = (const int*)d_in[1];   // [2,E] int32
    const float* Ws      = (const float*)d_in[3]; // [3,32,128]
    const float* att_src = (const float*)d_in[4]; // [3,4,32]
    const float* att_dst = (const float*)d_in[5];
    const float* bias    = (const float*)d_in[6]; // [3,32]

    int N = in_sizes[0] / 32;
    int E = in_sizes[1] / 2;
    const int* srcv = ei;
    const int* dstv = ei + E;

    // workspace layout
    float* fws   = (float*)d_ws;
    __half* h16  = (__half*)fws;                        // N*128 halves
    float* asrc  = (float*)(h16 + (size_t)N * 128);     // N*4
    float* adst  = asrc + (size_t)N * 4;                // N*4
    float* xbuf  = adst + (size_t)N * 4;                // N*32
    int*   deg    = (int*)(xbuf + (size_t)N * 32);      // N
    int*   rowst  = deg + N;                            // N+1
    int*   bsums  = rowst + N + 1;                      // 512
    int*   boffs  = bsums + 512;                        // 512
    int*   col    = boffs + 512;                        // E
    int*   rank   = col + E;                            // E

    int nb256 = (N + 255) / 256;           // <=512 for scan2
    int gemmBlocks = (N + 63) / 64;
    int edgeBlocks8 = (E + 8 * 256 - 1) / (8 * 256);

    hipMemsetAsync(deg, 0, (size_t)N * sizeof(int), stream);

    for (int l = 0; l < 3; ++l) {
        const float* xin = (l == 0) ? x : xbuf;
        float* xout = (l == 2) ? (float*)d_out : xbuf;
        int extra = (l == 0) ? edgeBlocks8 : 0;
        k_gemm_alpha<<<gemmBlocks + extra, 256, 0, stream>>>(
            xin, Ws + (size_t)l * 32 * 128, att_src + l * 128, att_dst + l * 128,
            h16, asrc, adst, N, dstv, E, deg, rank, gemmBlocks);
        if (l == 0) {
            k_scan1<<<nb256, 256, 0, stream>>>(deg, N, bsums);
            k_scan2<<<1, 512, 0, stream>>>(bsums, nb256, boffs);
            k_scan3<<<nb256, 256, 0, stream>>>(deg, N, boffs, rowst);
            k_scatter<<<edgeBlocks8, 256, 0, stream>>>(srcv, dstv, rank, rowst, E, col);
        }
        k_agg<<<(N + 3) / 4, 256, 0, stream>>>(
            h16, asrc, adst, rowst, col, bias + l * 32, xout, N);
    }
}